// Round 6
// baseline (111.468 us; speedup 1.0000x reference)
//
#include <hip/hip_runtime.h>
#include <stdint.h>

// Single-layer LSTM, input=1, hidden=1, zero init. One thread per row, serial over T.
// Wall time = 1024 steps x per-step critical-path latency (all rows fully parallel
// across waves; extra occupancy cannot shorten any chain). Two levers only:
//   (1) remove ALL exposed memory latency -> LDS double-buffer via global_load_lds
//       (compiler cannot sink it; 1 wave/block so s_waitcnt vmcnt(0) is the sync)
//   (2) shorten the chain: one rcp for the whole c-update (i,f,g merged), state
//       kept as rc = rcp(1+Ec); products tree-balanced so post-exp2 glue is minimal.
// Chain per step: u(fma)->exp2->add->mul->rcp->mul->exp2->add->rcp->fma ~ 4 trans + 5 VALU.

#define LOG2E 1.44269504088896340736f

typedef const unsigned int __attribute__((address_space(1)))* gas_ptr;
typedef unsigned int __attribute__((address_space(3)))* las_ptr;

__device__ __forceinline__ void gload_lds16(const float* g, float* l) {
    // 16B per lane; LDS dest = uniform base + lane*16 (pass base of the 64-lane slab).
    __builtin_amdgcn_global_load_lds((gas_ptr)(const void*)g, (las_ptr)(void*)l, 16, 0, 0);
}

__global__ __launch_bounds__(64) void lstm_h1_kernel(
    const float* __restrict__ x,
    const float* __restrict__ w_ih,
    const float* __restrict__ w_hh,
    const float* __restrict__ b_ih,
    const float* __restrict__ b_hh,
    float* __restrict__ out,
    int B, int T)
{
    __shared__ float4 xbuf[2][8][64];   // 2 x 8KB double buffer: [buf][group][lane]

    const int lane = threadIdx.x;                 // one wave per block
    const int row  = blockIdx.x * 64 + lane;
    if (row >= B) return;                          // B % 64 == 0 in practice

    // Gate order: i, f, g, o. Combined bias.
    const float b0 = b_ih[0] + b_hh[0];
    const float b1 = b_ih[1] + b_hh[1];
    const float b2 = b_ih[2] + b_hh[2];
    const float b3 = b_ih[3] + b_hh[3];

    // Scaled coefficients: sigmoid gates by -L, tanh gate by -2L.
    const float ciw = -LOG2E * w_ih[0],        cib = -LOG2E * b0,        cih = -LOG2E * w_hh[0];
    const float cfw = -LOG2E * w_ih[1],        cfb = -LOG2E * b1,        cfh = -LOG2E * w_hh[1];
    const float cgw = -2.0f * LOG2E * w_ih[2], cgb = -2.0f * LOG2E * b2, cgh = -2.0f * LOG2E * w_hh[2];
    const float cow = -LOG2E * w_ih[3],        cob = -LOG2E * b3,        coh = -LOG2E * w_hh[3];
    const float n2L = -2.0f * LOG2E;             // cs = n2L * c

    const float c2ih = 2.0f * cih, c2fh = 2.0f * cfh, c2gh = 2.0f * cgh, c2oh = 2.0f * coh;

    // State: rc = rcp(1+2^cs) (rc0=0.5 <=> tanh(c0)=0), cs = n2L*c, so_prev (0 => u=a).
    float rc = 0.5f, cs = 0.0f, so = 0.0f;

    const float* __restrict__ xrow = x + (size_t)row * T;
    float4* __restrict__ yr = reinterpret_cast<float4*>(out + (size_t)row * T);

#define LSTM_STEP(xx, hout)                                                   \
    {                                                                         \
        const float _x = (xx);                                                \
        /* x-dependent pre-activations (off-chain) */                         \
        float ai = fmaf(_x, ciw, cib);                                        \
        float af = fmaf(_x, cfw, cfb);                                        \
        float ag = fmaf(_x, cgw, cgb);                                        \
        float ao = fmaf(_x, cow, cob);                                        \
        /* prev-step h folded: u = fma(rc, p2, am)  (so = prev sigmoid(o)) */ \
        float p2i = c2ih * so, p2f = c2fh * so, p2g = c2gh * so, p2o = c2oh * so; \
        float ami = fmaf(cih, -so, ai);                                       \
        float amf = fmaf(cfh, -so, af);                                       \
        float amg = fmaf(cgh, -so, ag);                                       \
        float amo = fmaf(coh, -so, ao);                                       \
        float ui = fmaf(rc, p2i, ami);                                        \
        float uf = fmaf(rc, p2f, amf);                                        \
        float ug = fmaf(rc, p2g, amg);                                        \
        float uo = fmaf(rc, p2o, amo);                                        \
        float Ei = __builtin_amdgcn_exp2f(ui);                                \
        float Ef = __builtin_amdgcn_exp2f(uf);                                \
        float Eg = __builtin_amdgcn_exp2f(ug);                                \
        float Eo = __builtin_amdgcn_exp2f(uo);                                \
        float di = 1.0f + Ei;                                                 \
        float df = 1.0f + Ef;                                                 \
        float dg = 1.0f + Eg;                                                 \
        float dd = 1.0f + Eo;                                                 \
        /* tree-balanced so only {D2|csD} -> num -> Q2 -> cs sits after di */ \
        float dgdf = dg * df;                                                 \
        float csdg = cs * dg;                                                 \
        float nt   = fmaf(n2L, -Eg, n2L);      /* n2L*(1-Eg) */               \
        float ntdf = nt * df;                                                 \
        float D2   = di * dgdf;                                               \
        float csD  = csdg * di;                                               \
        float num  = csD + ntdf;                                              \
        float Q2   = __builtin_amdgcn_rcpf(D2);                               \
        so = __builtin_amdgcn_rcpf(dd);        /* off critical path */        \
        cs = num * Q2;                                                        \
        float Ec = __builtin_amdgcn_exp2f(cs);                                \
        float dc = 1.0f + Ec;                                                 \
        rc = __builtin_amdgcn_rcpf(dc);                                       \
        float tc = fmaf(2.0f, rc, -1.0f);                                     \
        (hout) = so * tc;                                                     \
    }

    // ---- prologue: stage chunk 0 (8 groups x 16B/lane) into buffer 0 ----
    #pragma unroll
    for (int j = 0; j < 8; ++j)
        gload_lds16(xrow + j * 4, (float*)&xbuf[0][j][0]);

    const int nChunks = T >> 5;   // 32 steps per chunk
    int p = 0;

    for (int c = 0; c < nChunks; ++c) {
        // Wait for the staged loads of buffer p (also drains old stores; they're long done).
        asm volatile("s_waitcnt vmcnt(0)" ::: "memory");

        // Prefetch next chunk into the other buffer (fire-and-forget, no VGPR cost).
        if (c + 1 < nChunks) {
            const float* nx = xrow + (c + 1) * 32;
            #pragma unroll
            for (int j = 0; j < 8; ++j)
                gload_lds16(nx + j * 4, (float*)&xbuf[p ^ 1][j][0]);
        }

        // Compute 32 steps from buffer p, reading one 16B group ahead.
        float4 xv = xbuf[p][0][lane];
        #pragma unroll
        for (int j = 0; j < 8; ++j) {
            float4 xn = xbuf[p][(j + 1) & 7][lane];   // j=7: dummy re-read (unused)
            float4 hv;
            LSTM_STEP(xv.x, hv.x);
            LSTM_STEP(xv.y, hv.y);
            LSTM_STEP(xv.z, hv.z);
            LSTM_STEP(xv.w, hv.w);
            yr[c * 8 + j] = hv;
            xv = xn;
        }
        p ^= 1;
    }
#undef LSTM_STEP
}

extern "C" void kernel_launch(void* const* d_in, const int* in_sizes, int n_in,
                              void* d_out, int out_size, void* d_ws, size_t ws_size,
                              hipStream_t stream) {
    const float* x    = (const float*)d_in[0];
    const float* w_ih = (const float*)d_in[1];
    const float* w_hh = (const float*)d_in[2];
    const float* b_ih = (const float*)d_in[3];
    const float* b_hh = (const float*)d_in[4];
    float* out = (float*)d_out;

    const int T = 1024;
    const int B = in_sizes[0] / T;  // x has B*T*1 elements

    const int block = 64;           // exactly one wave per block
    const int grid = (B + block - 1) / block;
    lstm_h1_kernel<<<grid, block, 0, stream>>>(x, w_ih, w_hh, b_ih, b_hh, out, B, T);
}

// Round 9
// 88.538 us; speedup vs baseline: 1.2590x; 1.2590x over previous
//
#include <hip/hip_runtime.h>

// Single-layer LSTM, input=1, hidden=1, zero init. One thread per row, serial over T.
// R9: NO inline-asm VMEM (R8's asm pipeline silently wrote nothing). Instead:
// double-buffered register ring (2 x 8 float4) with sched_barrier(0) fences.
// Plain C++ loads/stores -> compiler's waitcnt pass emits exact counted vmcnt(N)
// per register (correct by construction); sched_barrier(0) after each 8-load
// block prevents the scheduler from sinking loads to their uses (the collapse
// R5's VGPR=36 proved). One chunk (32 steps ~4500cy) of compute covers ~900cy
// HBM latency. LSTM step math identical to R6's verified version (absmax 9.77e-4).

#define LOG2E 1.44269504088896340736f

typedef float __attribute__((ext_vector_type(4))) f32x4;

__global__ __launch_bounds__(64) void lstm_h1_kernel(
    const float* __restrict__ x,
    const float* __restrict__ w_ih,
    const float* __restrict__ w_hh,
    const float* __restrict__ b_ih,
    const float* __restrict__ b_hh,
    float* __restrict__ out,
    int B, int T)
{
    const int row = blockIdx.x * 64 + (int)threadIdx.x;
    if (row >= B) return;   // B % 64 == 0 in practice

    // Gate order: i, f, g, o. Combined bias.
    const float b0 = b_ih[0] + b_hh[0];
    const float b1 = b_ih[1] + b_hh[1];
    const float b2 = b_ih[2] + b_hh[2];
    const float b3 = b_ih[3] + b_hh[3];

    // Scaled coefficients: sigmoid gates by -L, tanh gate by -2L.
    const float ciw = -LOG2E * w_ih[0],        cib = -LOG2E * b0,        cih = -LOG2E * w_hh[0];
    const float cfw = -LOG2E * w_ih[1],        cfb = -LOG2E * b1,        cfh = -LOG2E * w_hh[1];
    const float cgw = -2.0f * LOG2E * w_ih[2], cgb = -2.0f * LOG2E * b2, cgh = -2.0f * LOG2E * w_hh[2];
    const float cow = -LOG2E * w_ih[3],        cob = -LOG2E * b3,        coh = -LOG2E * w_hh[3];
    const float n2L = -2.0f * LOG2E;            // cs = n2L * c

    const float c2ih = 2.0f * cih, c2fh = 2.0f * cfh, c2gh = 2.0f * cgh, c2oh = 2.0f * coh;

    // State: rc = rcp(1+2^cs) (rc0=0.5 <=> tanh(c0)=0), cs = n2L*c, so_prev (0 => u=a).
    float rc = 0.5f, cs = 0.0f, so = 0.0f;

    const f32x4* __restrict__ xr4 = reinterpret_cast<const f32x4*>(x + (size_t)row * T);
    f32x4* __restrict__ yr4 = reinterpret_cast<f32x4*>(out + (size_t)row * T);

#define LSTM_STEP(xx, hout)                                                   \
    {                                                                         \
        const float _x = (xx);                                                \
        float ai = fmaf(_x, ciw, cib);                                        \
        float af = fmaf(_x, cfw, cfb);                                        \
        float ag = fmaf(_x, cgw, cgb);                                        \
        float ao = fmaf(_x, cow, cob);                                        \
        float p2i = c2ih * so, p2f = c2fh * so, p2g = c2gh * so, p2o = c2oh * so; \
        float ami = fmaf(cih, -so, ai);                                       \
        float amf = fmaf(cfh, -so, af);                                       \
        float amg = fmaf(cgh, -so, ag);                                       \
        float amo = fmaf(coh, -so, ao);                                       \
        float ui = fmaf(rc, p2i, ami);                                        \
        float uf = fmaf(rc, p2f, amf);                                        \
        float ug = fmaf(rc, p2g, amg);                                        \
        float uo = fmaf(rc, p2o, amo);                                        \
        float Ei = __builtin_amdgcn_exp2f(ui);                                \
        float Ef = __builtin_amdgcn_exp2f(uf);                                \
        float Eg = __builtin_amdgcn_exp2f(ug);                                \
        float Eo = __builtin_amdgcn_exp2f(uo);                                \
        float di = 1.0f + Ei;                                                 \
        float df = 1.0f + Ef;                                                 \
        float dg = 1.0f + Eg;                                                 \
        float dd = 1.0f + Eo;                                                 \
        float dgdf = dg * df;                                                 \
        float csdg = cs * dg;                                                 \
        float nt   = fmaf(n2L, -Eg, n2L);      /* n2L*(1-Eg) */               \
        float ntdf = nt * df;                                                 \
        float D2   = di * dgdf;                                               \
        float csD  = csdg * di;                                               \
        float num  = csD + ntdf;                                              \
        float Q2   = __builtin_amdgcn_rcpf(D2);                               \
        so = __builtin_amdgcn_rcpf(dd);        /* off critical path */        \
        cs = num * Q2;                                                        \
        float Ec = __builtin_amdgcn_exp2f(cs);                                \
        float dc = 1.0f + Ec;                                                 \
        rc = __builtin_amdgcn_rcpf(dc);                                       \
        float tc = fmaf(2.0f, rc, -1.0f);                                     \
        (hout) = so * tc;                                                     \
    }

#define GROUP(bufv, sp)                                                       \
    {                                                                         \
        f32x4 hv;                                                             \
        LSTM_STEP((bufv)[0], hv[0]);                                          \
        LSTM_STEP((bufv)[1], hv[1]);                                          \
        LSTM_STEP((bufv)[2], hv[2]);                                          \
        LSTM_STEP((bufv)[3], hv[3]);                                          \
        *(sp) = hv;                                                           \
    }

    // Ring A: current chunk. Ring B: next chunk. 8 float4 groups = 32 steps each.
    f32x4 a0, a1, a2, a3, a4, a5, a6, a7;
    f32x4 q0, q1, q2, q3, q4, q5, q6, q7;

    // Prologue: A = chunk 0.
    a0 = xr4[0]; a1 = xr4[1]; a2 = xr4[2]; a3 = xr4[3];
    a4 = xr4[4]; a5 = xr4[5]; a6 = xr4[6]; a7 = xr4[7];

    for (int it = 0; it < 16; ++it) {
        const int cA = 2 * it, cB = 2 * it + 1;

        // Load B = chunk cA+1 (cA+1 <= 31 always).
        {
            const f32x4* p = xr4 + (cA + 1) * 8;
            q0 = p[0]; q1 = p[1]; q2 = p[2]; q3 = p[3];
            q4 = p[4]; q5 = p[5]; q6 = p[6]; q7 = p[7];
        }
        __builtin_amdgcn_sched_barrier(0);   // loads may not sink below here

        // Compute chunk cA from A.
        {
            f32x4* ys = yr4 + cA * 8;
            GROUP(a0, ys + 0); GROUP(a1, ys + 1); GROUP(a2, ys + 2); GROUP(a3, ys + 3);
            GROUP(a4, ys + 4); GROUP(a5, ys + 5); GROUP(a6, ys + 6); GROUP(a7, ys + 7);
        }

        // Load A = chunk cB+1 (clamped: it=15 reloads chunk 31 harmlessly).
        {
            const int nc = (cB + 1 < 32) ? (cB + 1) : 31;
            const f32x4* p = xr4 + nc * 8;
            a0 = p[0]; a1 = p[1]; a2 = p[2]; a3 = p[3];
            a4 = p[4]; a5 = p[5]; a6 = p[6]; a7 = p[7];
        }
        __builtin_amdgcn_sched_barrier(0);   // loads may not sink below here

        // Compute chunk cB from B.
        {
            f32x4* ys = yr4 + cB * 8;
            GROUP(q0, ys + 0); GROUP(q1, ys + 1); GROUP(q2, ys + 2); GROUP(q3, ys + 3);
            GROUP(q4, ys + 4); GROUP(q5, ys + 5); GROUP(q6, ys + 6); GROUP(q7, ys + 7);
        }
    }

#undef GROUP
#undef LSTM_STEP
}

extern "C" void kernel_launch(void* const* d_in, const int* in_sizes, int n_in,
                              void* d_out, int out_size, void* d_ws, size_t ws_size,
                              hipStream_t stream) {
    const float* x    = (const float*)d_in[0];
    const float* w_ih = (const float*)d_in[1];
    const float* w_hh = (const float*)d_in[2];
    const float* b_ih = (const float*)d_in[3];
    const float* b_hh = (const float*)d_in[4];
    float* out = (float*)d_out;

    const int T = 1024;
    const int B = in_sizes[0] / T;  // x has B*T*1 elements

    const int block = 64;           // one wave per block
    const int grid = (B + block - 1) / block;
    lstm_h1_kernel<<<grid, block, 0, stream>>>(x, w_ih, w_hh, b_ih, b_hh, out, B, T);
}